// Round 1
// baseline (84.681 us; speedup 1.0000x reference)
//
#include <hip/hip_runtime.h>

// AttentionCore64: B=2,H=16,S=2048,D=64, fp32 in/out, softmax(QK^T)V, NO 1/sqrt(d).
// Flash attention, f16 MFMA 32x32x16, swapped QK^T (S^T = K*Q^T) so softmax is
// lane-local (+1 shfl_xor(32)). K in LDS as [k][d], V as V^T [d][k], both
// XOR-swizzled. Online softmax (mathematically identical to reference's raw exp).

#define LOG2E 1.44269504088896340736f

typedef _Float16 half8 __attribute__((ext_vector_type(8)));
typedef _Float16 half4 __attribute__((ext_vector_type(4)));
typedef float f32x16 __attribute__((ext_vector_type(16)));

#define BH    32
#define SEQ   2048
#define DIM   64
#define QBLK  128   // per block (4 waves x 32 q-rows)
#define KVBLK 64
#define NT    (SEQ / KVBLK)   // 32 kv tiles

__launch_bounds__(256, 2)
__global__ void attn_fwd(const float* __restrict__ Q, const float* __restrict__ K,
                         const float* __restrict__ V, float* __restrict__ O) {
  // LDS: K-tile [64][64] f16 (row-major, swizzled), V^T-tile [64][64] f16
  __shared__ _Float16 lK[KVBLK * DIM];
  __shared__ _Float16 lVt[DIM * KVBLK];

  const int tid  = threadIdx.x;
  const int lane = tid & 63;
  const int wave = tid >> 6;
  const int hi   = lane >> 5;   // which half of the wave (k-group for MFMA frags)
  const int lq   = lane & 31;   // q-row within wave's 32-row tile

  // XCD-aware swizzle: all 16 q-tiles of one (b,h) -> same XCD (K/V L2 locality).
  // grid=512=8*64; dispatch round-robins bid%8 across XCDs.
  const int bid  = blockIdx.x;
  const int xcd  = bid & 7;
  const int slot = bid >> 3;          // 0..63
  const int bh   = xcd + 8 * (slot >> 4);  // 0..31
  const int qt   = slot & 15;         // 0..15

  const size_t base = (size_t)bh * SEQ * DIM;
  const int qrow = qt * QBLK + wave * 32 + lq;
  const float* qp = Q + base + (size_t)qrow * DIM;

  // Q fragments (B-operand of S^T = K*Q^T): lane holds Q[q=lq][d = 16c + 8hi + j]
  half8 qfrag[4];
#pragma unroll
  for (int c = 0; c < 4; ++c) {
    float4 a = *(const float4*)(qp + 16 * c + 8 * hi);
    float4 b = *(const float4*)(qp + 16 * c + 8 * hi + 4);
    half8 h;
    h[0] = (_Float16)a.x; h[1] = (_Float16)a.y; h[2] = (_Float16)a.z; h[3] = (_Float16)a.w;
    h[4] = (_Float16)b.x; h[5] = (_Float16)b.y; h[6] = (_Float16)b.z; h[7] = (_Float16)b.w;
    qfrag[c] = h;
  }

  f32x16 oacc0 = {};  // O^T rows d=0..31  (lane: d=(r&3)+8*(r>>2)+4*hi, col q=lq)
  f32x16 oacc1 = {};  // O^T rows d=32..63
  float m = -1e30f, lsum = 0.f;

  // ---- reg-staged prefetch buffers ----
  float4 kreg[4];
  float vreg0[8], vreg1[8];
  const int vd  = tid & 63;          // d column this thread stages for V^T
  const int vk0 = (tid >> 6) * 16;   // k range start
  const float* kbp = K + base;
  const float* vbp = V + base;

  auto LOADT = [&](int t) {
    const float* kp = kbp + (size_t)t * KVBLK * DIM;
#pragma unroll
    for (int i = 0; i < 4; ++i) {
      int e = i * 1024 + tid * 4;
      int kr = e >> 6, d = e & 63;
      kreg[i] = *(const float4*)(kp + kr * DIM + d);
    }
    const float* vp = vbp + (size_t)t * KVBLK * DIM + vd;
#pragma unroll
    for (int i = 0; i < 8; ++i) vreg0[i] = vp[(vk0 + i) * DIM];
#pragma unroll
    for (int i = 0; i < 8; ++i) vreg1[i] = vp[(vk0 + 8 + i) * DIM];
  };

  auto STORET = [&]() {
#pragma unroll
    for (int i = 0; i < 4; ++i) {
      int e = i * 1024 + tid * 4;
      int kr = e >> 6, d = e & 63;
      half4 h;
      h[0] = (_Float16)kreg[i].x; h[1] = (_Float16)kreg[i].y;
      h[2] = (_Float16)kreg[i].z; h[3] = (_Float16)kreg[i].w;
      int idx = (kr * 64 + d) ^ ((kr & 7) << 3);   // swizzle bits 3-5 (16B units)
      *(half4*)&lK[idx] = h;
    }
    half8 a, b;
#pragma unroll
    for (int i = 0; i < 8; ++i) a[i] = (_Float16)vreg0[i];
#pragma unroll
    for (int i = 0; i < 8; ++i) b[i] = (_Float16)vreg1[i];
    int i0 = (vd * 64 + vk0) ^ ((vd & 7) << 3);
    *(half8*)&lVt[i0] = a;
    int i1 = (vd * 64 + vk0 + 8) ^ ((vd & 7) << 3);
    *(half8*)&lVt[i1] = b;
  };

  LOADT(0);
  for (int t = 0; t < NT; ++t) {
    __syncthreads();                 // previous tile's LDS reads done
    STORET();
    if (t + 1 < NT) LOADT(t + 1);    // prefetch overlaps compute below
    __syncthreads();

#pragma unroll
    for (int kblk = 0; kblk < 2; ++kblk) {
      // ---- QK^T: S^T[32k x 32q] = K_tile * Q^T, split acc to break dep chain
      const int krow = kblk * 32 + lq;
      const int kswz = (krow & 7) << 3;
      f32x16 sa = {}, sb = {};
      {
        half8 a0 = *(const half8*)&lK[(krow * 64 +  0 + hi * 8) ^ kswz];
        half8 a1 = *(const half8*)&lK[(krow * 64 + 16 + hi * 8) ^ kswz];
        half8 a2 = *(const half8*)&lK[(krow * 64 + 32 + hi * 8) ^ kswz];
        half8 a3 = *(const half8*)&lK[(krow * 64 + 48 + hi * 8) ^ kswz];
        sa = __builtin_amdgcn_mfma_f32_32x32x16_f16(a0, qfrag[0], sa, 0, 0, 0);
        sb = __builtin_amdgcn_mfma_f32_32x32x16_f16(a1, qfrag[1], sb, 0, 0, 0);
        sa = __builtin_amdgcn_mfma_f32_32x32x16_f16(a2, qfrag[2], sa, 0, 0, 0);
        sb = __builtin_amdgcn_mfma_f32_32x32x16_f16(a3, qfrag[3], sb, 0, 0, 0);
      }
      float s[16];
#pragma unroll
      for (int i = 0; i < 16; ++i) s[i] = sa[i] + sb[i];

      // ---- online softmax (lane holds 16 of 32 k-rows; partner lane^32 the rest)
      float tmax = s[0];
#pragma unroll
      for (int i = 1; i < 16; ++i) tmax = fmaxf(tmax, s[i]);
      tmax = fmaxf(tmax, __shfl_xor(tmax, 32));
      float mn = fmaxf(m, tmax);
      float corr = __builtin_amdgcn_exp2f((m - mn) * LOG2E);
      float p[16];
      float ts = 0.f;
#pragma unroll
      for (int i = 0; i < 16; ++i) {
        p[i] = __builtin_amdgcn_exp2f((s[i] - mn) * LOG2E);
        ts += p[i];
      }
      ts += __shfl_xor(ts, 32);
      lsum = lsum * corr + ts;
      m = mn;
#pragma unroll
      for (int i = 0; i < 16; ++i) { oacc0[i] *= corr; oacc1[i] *= corr; }

      // ---- pack P to f16 pairs, exchange with lane^32 to build B-fragments.
      // reg r -> S^T row (r&3)+8*(r>>2)+4*hi, so:
      //   w0=(rows 0,1)+4hi  w1=(2,3)+4hi  w2=(8,9)+4hi   w3=(10,11)+4hi
      //   w4=(16,17)+4hi     w5=(18,19)+4hi w6=(24,25)+4hi w7=(26,27)+4hi
      // B-frag chunk0 (k 0..15):  hi0 {w0,w1,ow0,ow1}  hi1 {ow2,ow3,w2,w3}
      // B-frag chunk1 (k 16..31): hi0 {w4,w5,ow4,ow5}  hi1 {ow6,ow7,w6,w7}
      unsigned w[8], ow[8];
#pragma unroll
      for (int i = 0; i < 8; ++i) {
        union { _Float16 h[2]; unsigned u; } cv;
        cv.h[0] = (_Float16)p[2 * i];
        cv.h[1] = (_Float16)p[2 * i + 1];
        w[i] = cv.u;
      }
#pragma unroll
      for (int i = 0; i < 8; ++i) ow[i] = (unsigned)__shfl_xor((int)w[i], 32);

      union { unsigned u[4]; half8 v; } pf0, pf1;
      if (hi == 0) {
        pf0.u[0] = w[0];  pf0.u[1] = w[1];  pf0.u[2] = ow[0]; pf0.u[3] = ow[1];
        pf1.u[0] = w[4];  pf1.u[1] = w[5];  pf1.u[2] = ow[4]; pf1.u[3] = ow[5];
      } else {
        pf0.u[0] = ow[2]; pf0.u[1] = ow[3]; pf0.u[2] = w[2];  pf0.u[3] = w[3];
        pf1.u[0] = ow[6]; pf1.u[1] = ow[7]; pf1.u[2] = w[6];  pf1.u[3] = w[7];
      }

      // ---- PV: O^T += V^T * P^T  (alternate accumulators -> independent MFMAs)
      const int d0 = lq, d1 = 32 + lq;
      const int sz0 = (d0 & 7) << 3, sz1 = (d1 & 7) << 3;
      {
        half8 a = *(const half8*)&lVt[(d0 * 64 + kblk * 32 + 0 + hi * 8) ^ sz0];
        oacc0 = __builtin_amdgcn_mfma_f32_32x32x16_f16(a, pf0.v, oacc0, 0, 0, 0);
      }
      {
        half8 a = *(const half8*)&lVt[(d1 * 64 + kblk * 32 + 0 + hi * 8) ^ sz1];
        oacc1 = __builtin_amdgcn_mfma_f32_32x32x16_f16(a, pf0.v, oacc1, 0, 0, 0);
      }
      {
        half8 a = *(const half8*)&lVt[(d0 * 64 + kblk * 32 + 16 + hi * 8) ^ sz0];
        oacc0 = __builtin_amdgcn_mfma_f32_32x32x16_f16(a, pf1.v, oacc0, 0, 0, 0);
      }
      {
        half8 a = *(const half8*)&lVt[(d1 * 64 + kblk * 32 + 16 + hi * 8) ^ sz1];
        oacc1 = __builtin_amdgcn_mfma_f32_32x32x16_f16(a, pf1.v, oacc1, 0, 0, 0);
      }
    }
  }

  // ---- epilogue: O[q][d] = O^T[d][q] / lsum
  const float inv = 1.0f / lsum;
  float* op = O + base + (size_t)qrow * DIM;
#pragma unroll
  for (int g = 0; g < 4; ++g) {
    float4 r0, r1;
    r0.x = oacc0[4 * g + 0] * inv; r0.y = oacc0[4 * g + 1] * inv;
    r0.z = oacc0[4 * g + 2] * inv; r0.w = oacc0[4 * g + 3] * inv;
    r1.x = oacc1[4 * g + 0] * inv; r1.y = oacc1[4 * g + 1] * inv;
    r1.z = oacc1[4 * g + 2] * inv; r1.w = oacc1[4 * g + 3] * inv;
    *(float4*)(op + 8 * g + 4 * hi) = r0;        // d = 8g+4hi .. +3
    *(float4*)(op + 32 + 8 * g + 4 * hi) = r1;   // d = 32+8g+4hi .. +3
  }
}

extern "C" void kernel_launch(void* const* d_in, const int* in_sizes, int n_in,
                              void* d_out, int out_size, void* d_ws, size_t ws_size,
                              hipStream_t stream) {
  const float* q = (const float*)d_in[0];
  const float* k = (const float*)d_in[1];
  const float* v = (const float*)d_in[2];
  float* o = (float*)d_out;
  attn_fwd<<<BH * (SEQ / QBLK), 256, 0, stream>>>(q, k, v, o);
}

// Round 3
// 76.768 us; speedup vs baseline: 1.1031x; 1.1031x over previous
//
#include <hip/hip_runtime.h>

// AttentionCore64: B=2,H=16,S=2048,D=64, fp32 in/out, softmax(QK^T)V, NO 1/sqrt(d).
// R2b: in-block KV-split. 4 waves = 2 q-subtiles x 2 kv-parities -> grid 1024
// (4 blocks/CU, 4 waves/SIMD) with UNCHANGED total staging/MFMA volume.
// f16 MFMA 32x32x16, swapped QK^T (lane-local softmax), defer-max (THR=8),
// packed cvt_pkrtz, XOR-swizzled LDS. Final per-pair (m,l,O) combine via LDS.

#define LOG2E 1.44269504088896340736f

typedef _Float16 half8 __attribute__((ext_vector_type(8)));
typedef __fp16 fp16x2 __attribute__((ext_vector_type(2)));   // cvt_pkrtz return type
typedef float f32x16 __attribute__((ext_vector_type(16)));

#define BH   32
#define SEQ  2048
#define DIM  64
#define QBLK 64            // q rows per block (2 q-waves x 32)
#define KVB  32            // kv rows per tile (one parity)
#define NIT  (SEQ / (2 * KVB))   // 32 iterations, 2 tiles (parities) each

union SMem {
  struct { _Float16 K[2][KVB * DIM]; _Float16 Vt[2][DIM * KVB]; } s;   // 16 KB staging
  struct { float ob[2][32 * 64]; float m[2][64]; float l[2][64]; } c;  // 17 KB combine
};

static __device__ __forceinline__ unsigned pk2(float a, float b) {
  fp16x2 h = __builtin_amdgcn_cvt_pkrtz(a, b);
  return __builtin_bit_cast(unsigned, h);
}

__launch_bounds__(256, 4)
__global__ void attn_fwd(const float* __restrict__ Q, const float* __restrict__ K,
                         const float* __restrict__ V, float* __restrict__ O) {
  __shared__ __align__(16) SMem sm;

  const int tid  = threadIdx.x;
  const int lane = tid & 63;
  const int wave = tid >> 6;
  const int wq   = wave & 1;    // q sub-tile
  const int wk   = wave >> 1;   // kv parity
  const int hi   = lane >> 5;
  const int lq   = lane & 31;

  // XCD swizzle: 1024 = 8 xcd * 128; all 32 q-tiles of a bh on one XCD.
  const int bid  = blockIdx.x;
  const int xcd  = bid & 7;
  const int slot = bid >> 3;             // 0..127
  const int bh   = xcd + 8 * (slot >> 5); // 0..31
  const int qt   = slot & 31;            // 0..31

  const size_t base = (size_t)bh * SEQ * DIM;
  const int qrow = qt * QBLK + wq * 32 + lq;
  const float* qp = Q + base + (size_t)qrow * DIM;

  // Q fragments (B-operand of S^T = K*Q^T): lane holds Q[q=lq][d=16c+8hi+j]
  half8 qfrag[4];
#pragma unroll
  for (int c = 0; c < 4; ++c) {
    float4 a = *(const float4*)(qp + 16 * c + 8 * hi);
    float4 b = *(const float4*)(qp + 16 * c + 8 * hi + 4);
    union { unsigned u[4]; half8 v; } h;
    h.u[0] = pk2(a.x, a.y); h.u[1] = pk2(a.z, a.w);
    h.u[2] = pk2(b.x, b.y); h.u[3] = pk2(b.z, b.w);
    qfrag[c] = h.v;
  }

  f32x16 oacc0 = {};  // O^T rows d=(r&3)+8*(r>>2)+4*hi, col q=lq
  f32x16 oacc1 = {};  // same, d+32
  float m = -1e30f, lsum = 0.f;

  // ---- prefetch regs: per iteration stage 2 parity tiles of K and V ----
  float4 kreg[2][2];
  float  vreg[2][8];
  const int kr  = tid >> 3;          // K row this thread stages (0..31)
  const int kd  = (tid & 7) * 8;     // K d-offset
  const int vd  = tid & 63;          // V^T row (d)
  const int vk0 = (tid >> 6) * 8;    // V^T k-offset
  const float* kbp = K + base;
  const float* vbp = V + base;

  auto LOADT = [&](int it) {
#pragma unroll
    for (int p = 0; p < 2; ++p) {
      const int t = 2 * it + p;
      const float* kp = kbp + (size_t)(t * KVB + kr) * DIM + kd;
      kreg[p][0] = *(const float4*)(kp);
      kreg[p][1] = *(const float4*)(kp + 4);
      const float* vp = vbp + (size_t)(t * KVB + vk0) * DIM + vd;
#pragma unroll
      for (int j = 0; j < 8; ++j) vreg[p][j] = vp[j * DIM];
    }
  };

  auto STORET = [&]() {
#pragma unroll
    for (int p = 0; p < 2; ++p) {
      union { unsigned u[4]; half8 v; } h;
      h.u[0] = pk2(kreg[p][0].x, kreg[p][0].y);
      h.u[1] = pk2(kreg[p][0].z, kreg[p][0].w);
      h.u[2] = pk2(kreg[p][1].x, kreg[p][1].y);
      h.u[3] = pk2(kreg[p][1].z, kreg[p][1].w);
      const int idx = (kr * DIM + kd) ^ ((kr & 7) << 3);
      *(half8*)&sm.s.K[p][idx] = h.v;
      union { unsigned u[4]; half8 v; } g;
      g.u[0] = pk2(vreg[p][0], vreg[p][1]);
      g.u[1] = pk2(vreg[p][2], vreg[p][3]);
      g.u[2] = pk2(vreg[p][4], vreg[p][5]);
      g.u[3] = pk2(vreg[p][6], vreg[p][7]);
      const int vidx = (vd * KVB + vk0) ^ ((vd & 7) << 3);
      *(half8*)&sm.s.Vt[p][vidx] = g.v;
    }
  };

  LOADT(0);
  for (int it = 0; it < NIT; ++it) {
    __syncthreads();                 // prev tile's LDS reads done
    STORET();
    if (it + 1 < NIT) LOADT(it + 1); // prefetch overlaps compute
    __syncthreads();

    const _Float16* Kt = sm.s.K[wk];
    const _Float16* Vt = sm.s.Vt[wk];

    // ---- QK^T: S^T[32k x 32q], single acc chain (4 MFMA over d-chunks)
    const int ksw = (lq & 7) << 3;
    f32x16 sacc = {};
#pragma unroll
    for (int c = 0; c < 4; ++c) {
      half8 a = *(const half8*)&Kt[(lq * DIM + c * 16 + hi * 8) ^ ksw];
      sacc = __builtin_amdgcn_mfma_f32_32x32x16_f16(a, qfrag[c], sacc, 0, 0, 0);
    }
    float s[16];
#pragma unroll
    for (int i = 0; i < 16; ++i) s[i] = sacc[i];

    // ---- online softmax, defer-max (THR=8; f16 P bounded by e^8=2981)
    float tmax = s[0];
#pragma unroll
    for (int i = 1; i < 16; ++i) tmax = fmaxf(tmax, s[i]);
    tmax = fmaxf(tmax, __shfl_xor(tmax, 32));
    if (__any(tmax > m + 8.f)) {
      const float mn = fmaxf(m, tmax);
      const float corr = __builtin_amdgcn_exp2f((m - mn) * LOG2E);
      m = mn;
      lsum *= corr;
#pragma unroll
      for (int i = 0; i < 16; ++i) { oacc0[i] *= corr; oacc1[i] *= corr; }
    }
    float p[16];
    float ts = 0.f;
#pragma unroll
    for (int i = 0; i < 16; ++i) {
      p[i] = __builtin_amdgcn_exp2f((s[i] - m) * LOG2E);
      ts += p[i];
    }
    ts += __shfl_xor(ts, 32);
    lsum += ts;

    // ---- pack P (pkrtz) + exchange with lane^32 to build PV B-fragments
    unsigned w[8], ow[8];
#pragma unroll
    for (int i = 0; i < 8; ++i) w[i] = pk2(p[2 * i], p[2 * i + 1]);
#pragma unroll
    for (int i = 0; i < 8; ++i) ow[i] = (unsigned)__shfl_xor((int)w[i], 32);

    union { unsigned u[4]; half8 v; } pf0, pf1;
    if (hi == 0) {
      pf0.u[0] = w[0];  pf0.u[1] = w[1];  pf0.u[2] = ow[0]; pf0.u[3] = ow[1];
      pf1.u[0] = w[4];  pf1.u[1] = w[5];  pf1.u[2] = ow[4]; pf1.u[3] = ow[5];
    } else {
      pf0.u[0] = ow[2]; pf0.u[1] = ow[3]; pf0.u[2] = w[2];  pf0.u[3] = w[3];
      pf1.u[0] = ow[6]; pf1.u[1] = ow[7]; pf1.u[2] = w[6];  pf1.u[3] = w[7];
    }

    // ---- PV: O^T += V^T * P^T
    const int d0 = lq, d1 = 32 + lq;
    const int sz0 = (d0 & 7) << 3, sz1 = (d1 & 7) << 3;
    {
      half8 a = *(const half8*)&Vt[(d0 * KVB + 0 + hi * 8) ^ sz0];
      oacc0 = __builtin_amdgcn_mfma_f32_32x32x16_f16(a, pf0.v, oacc0, 0, 0, 0);
    }
    {
      half8 a = *(const half8*)&Vt[(d1 * KVB + 0 + hi * 8) ^ sz1];
      oacc1 = __builtin_amdgcn_mfma_f32_32x32x16_f16(a, pf0.v, oacc1, 0, 0, 0);
    }
    {
      half8 a = *(const half8*)&Vt[(d0 * KVB + 16 + hi * 8) ^ sz0];
      oacc0 = __builtin_amdgcn_mfma_f32_32x32x16_f16(a, pf1.v, oacc0, 0, 0, 0);
    }
    {
      half8 a = *(const half8*)&Vt[(d1 * KVB + 16 + hi * 8) ^ sz1];
      oacc1 = __builtin_amdgcn_mfma_f32_32x32x16_f16(a, pf1.v, oacc1, 0, 0, 0);
    }
  }

  // ---- combine the two kv-parities of each q sub-tile via LDS ----
  __syncthreads();  // all staging-LDS reads done before union reuse
  if (wk == 1) {
#pragma unroll
    for (int r = 0; r < 16; ++r) {
      sm.c.ob[wq][r * 64 + lane]        = oacc0[r];
      sm.c.ob[wq][(16 + r) * 64 + lane] = oacc1[r];
    }
    sm.c.m[wq][lane] = m;
    sm.c.l[wq][lane] = lsum;
  }
  __syncthreads();
  if (wk == 0) {
    const float mb = sm.c.m[wq][lane];
    const float lb = sm.c.l[wq][lane];
    const float mx = fmaxf(m, mb);
    const float ca = __builtin_amdgcn_exp2f((m - mx) * LOG2E);
    const float cb = __builtin_amdgcn_exp2f((mb - mx) * LOG2E);
    const float inv = 1.0f / (lsum * ca + lb * cb);

    float* op = O + base + (size_t)qrow * DIM;
#pragma unroll
    for (int g = 0; g < 4; ++g) {
      float4 r0, r1;
      r0.x = (oacc0[4 * g + 0] * ca + sm.c.ob[wq][(4 * g + 0) * 64 + lane] * cb) * inv;
      r0.y = (oacc0[4 * g + 1] * ca + sm.c.ob[wq][(4 * g + 1) * 64 + lane] * cb) * inv;
      r0.z = (oacc0[4 * g + 2] * ca + sm.c.ob[wq][(4 * g + 2) * 64 + lane] * cb) * inv;
      r0.w = (oacc0[4 * g + 3] * ca + sm.c.ob[wq][(4 * g + 3) * 64 + lane] * cb) * inv;
      r1.x = (oacc1[4 * g + 0] * ca + sm.c.ob[wq][(16 + 4 * g + 0) * 64 + lane] * cb) * inv;
      r1.y = (oacc1[4 * g + 1] * ca + sm.c.ob[wq][(16 + 4 * g + 1) * 64 + lane] * cb) * inv;
      r1.z = (oacc1[4 * g + 2] * ca + sm.c.ob[wq][(16 + 4 * g + 2) * 64 + lane] * cb) * inv;
      r1.w = (oacc1[4 * g + 3] * ca + sm.c.ob[wq][(16 + 4 * g + 3) * 64 + lane] * cb) * inv;
      *(float4*)(op + 8 * g + 4 * hi) = r0;        // d = 8g+4hi..+3
      *(float4*)(op + 32 + 8 * g + 4 * hi) = r1;   // d = 32+8g+4hi..+3
    }
  }
}

extern "C" void kernel_launch(void* const* d_in, const int* in_sizes, int n_in,
                              void* d_out, int out_size, void* d_ws, size_t ws_size,
                              hipStream_t stream) {
  const float* q = (const float*)d_in[0];
  const float* k = (const float*)d_in[1];
  const float* v = (const float*)d_in[2];
  float* o = (float*)d_out;
  attn_fwd<<<BH * (SEQ / QBLK), 256, 0, stream>>>(q, k, v, o);
}

// Round 5
// 67.347 us; speedup vs baseline: 1.2574x; 1.1399x over previous
//
#include <hip/hip_runtime.h>

// AttentionCore64: B=2,H=16,S=2048,D=64, fp32 in/out, softmax(QK^T)V, NO 1/sqrt(d).
// R5: R4 structure (64 q-rows/wave: each LDS K/V read feeds 2 MFMAs) with all
// cross-lane exchange via proven __shfl_xor(32). Pair-exchange trick: one
// shuffle + cndmask serves both directions of each word pair (4 shfl/set
// instead of 8). Defer-max, tree reductions, setprio. QBLK=128, grid=512.

#define LOG2E 1.44269504088896340736f

typedef _Float16 half8 __attribute__((ext_vector_type(8)));
typedef __fp16 fp16x2 __attribute__((ext_vector_type(2)));   // cvt_pkrtz return
typedef float f32x16 __attribute__((ext_vector_type(16)));

#define BH   32
#define SEQ  2048
#define DIM  64
#define QBLK 128             // 2 q-waves x 64 rows
#define KVB  32              // kv rows per parity tile
#define NIT  (SEQ / (2 * KVB))   // 32 iterations

union SMem {
  struct { _Float16 K[2][KVB * DIM]; _Float16 Vt[2][DIM * KVB]; } s;     // 16 KB
  struct { float ob[2][2][2][16 * 64]; float ml[2][2][2][64]; } c;       // 36 KB
};

static __device__ __forceinline__ unsigned pk2(float a, float b) {
  fp16x2 h = __builtin_amdgcn_cvt_pkrtz(a, b);
  return __builtin_bit_cast(unsigned, h);
}

static __device__ __forceinline__ float xmax32(float x) {
  return fmaxf(x, __shfl_xor(x, 32));
}
static __device__ __forceinline__ float xsum32(float x) {
  return x + __shfl_xor(x, 32);
}

__launch_bounds__(256, 2)
__global__ void attn_fwd(const float* __restrict__ Q, const float* __restrict__ K,
                         const float* __restrict__ V, float* __restrict__ O) {
  __shared__ __align__(16) SMem sm;

  const int tid  = threadIdx.x;
  const int lane = tid & 63;
  const int wave = tid >> 6;
  const int wq   = wave & 1;    // q sub-tile (64 rows)
  const int wk   = wave >> 1;   // kv parity
  const int hi   = lane >> 5;
  const int lq   = lane & 31;
  const bool hb  = (hi != 0);

  // XCD swizzle: 512 = 8 xcd * 64; all 16 q-tiles of a bh on one XCD.
  const int bid  = blockIdx.x;
  const int xcd  = bid & 7;
  const int slot = bid >> 3;               // 0..63
  const int bh   = xcd + 8 * (slot >> 4);  // 0..31
  const int qt   = slot & 15;              // 0..15

  const size_t base = (size_t)bh * SEQ * DIM;
  const int qr0 = qt * QBLK + wq * 64 + lq;   // set A row; set B = +32
  const float* qpA = Q + base + (size_t)qr0 * DIM;
  const float* qpB = qpA + 32 * DIM;

  // Q fragments (B-operand of S^T = K*Q^T): lane holds Q[q][d=16c+8hi+j]
  half8 qfA[4], qfB[4];
#pragma unroll
  for (int c = 0; c < 4; ++c) {
    float4 a0 = *(const float4*)(qpA + 16 * c + 8 * hi);
    float4 a1 = *(const float4*)(qpA + 16 * c + 8 * hi + 4);
    union { unsigned u[4]; half8 v; } h;
    h.u[0] = pk2(a0.x, a0.y); h.u[1] = pk2(a0.z, a0.w);
    h.u[2] = pk2(a1.x, a1.y); h.u[3] = pk2(a1.z, a1.w);
    qfA[c] = h.v;
    float4 b0 = *(const float4*)(qpB + 16 * c + 8 * hi);
    float4 b1 = *(const float4*)(qpB + 16 * c + 8 * hi + 4);
    h.u[0] = pk2(b0.x, b0.y); h.u[1] = pk2(b0.z, b0.w);
    h.u[2] = pk2(b1.x, b1.y); h.u[3] = pk2(b1.z, b1.w);
    qfB[c] = h.v;
  }

  f32x16 oA0 = {}, oA1 = {}, oB0 = {}, oB1 = {};   // O^T: d=(r&3)+8*(r>>2)+4hi (+32), q=lq
  float mA = -1e30f, lA = 0.f, mB = -1e30f, lB = 0.f;

  // ---- prefetch regs: stage both parity tiles of K and V per iteration ----
  float4 kreg[2][2];
  float  vreg[2][8];
  const int kr  = tid >> 3;          // K row (0..31)
  const int kd  = (tid & 7) * 8;     // K d-offset
  const int vd  = tid & 63;          // V^T row (d)
  const int vk0 = (tid >> 6) * 8;    // V^T k-offset
  const float* kbp = K + base;
  const float* vbp = V + base;

  auto LOADT = [&](int it) {
#pragma unroll
    for (int p = 0; p < 2; ++p) {
      const int t = 2 * it + p;
      const float* kp = kbp + (size_t)(t * KVB + kr) * DIM + kd;
      kreg[p][0] = *(const float4*)(kp);
      kreg[p][1] = *(const float4*)(kp + 4);
      const float* vp = vbp + (size_t)(t * KVB + vk0) * DIM + vd;
#pragma unroll
      for (int j = 0; j < 8; ++j) vreg[p][j] = vp[j * DIM];
    }
  };

  auto STORET = [&]() {
#pragma unroll
    for (int p = 0; p < 2; ++p) {
      union { unsigned u[4]; half8 v; } h;
      h.u[0] = pk2(kreg[p][0].x, kreg[p][0].y);
      h.u[1] = pk2(kreg[p][0].z, kreg[p][0].w);
      h.u[2] = pk2(kreg[p][1].x, kreg[p][1].y);
      h.u[3] = pk2(kreg[p][1].z, kreg[p][1].w);
      const int idx = (kr * DIM + kd) ^ ((kr & 7) << 3);
      *(half8*)&sm.s.K[p][idx] = h.v;
      union { unsigned u[4]; half8 v; } g;
      g.u[0] = pk2(vreg[p][0], vreg[p][1]);
      g.u[1] = pk2(vreg[p][2], vreg[p][3]);
      g.u[2] = pk2(vreg[p][4], vreg[p][5]);
      g.u[3] = pk2(vreg[p][6], vreg[p][7]);
      const int vidx = (vd * KVB + vk0) ^ ((vd & 7) << 3);
      *(half8*)&sm.s.Vt[p][vidx] = g.v;
    }
  };

  // softmax for one fragment set; emits PV B-fragments pv0 (k0..15), pv1 (k16..31)
  auto softmax_set = [&](const f32x16& s, float& m, float& l,
                         f32x16& o0, f32x16& o1, half8& pv0, half8& pv1) {
    float x0 = fmaxf(fmaxf(s[0], s[1]), fmaxf(s[2], s[3]));
    float x1 = fmaxf(fmaxf(s[4], s[5]), fmaxf(s[6], s[7]));
    float x2 = fmaxf(fmaxf(s[8], s[9]), fmaxf(s[10], s[11]));
    float x3 = fmaxf(fmaxf(s[12], s[13]), fmaxf(s[14], s[15]));
    float t = xmax32(fmaxf(fmaxf(x0, x1), fmaxf(x2, x3)));
    if (__any(t > m + 8.f)) {          // defer-max: skip rescale for small growth
      const float mn = fmaxf(m, t);
      const float corr = __builtin_amdgcn_exp2f((m - mn) * LOG2E);
      m = mn; l *= corr;
#pragma unroll
      for (int i = 0; i < 16; ++i) { o0[i] *= corr; o1[i] *= corr; }
    }
    const float nml2 = -m * LOG2E;
    float p[16];
#pragma unroll
    for (int i = 0; i < 16; ++i)
      p[i] = __builtin_amdgcn_exp2f(__builtin_fmaf(s[i], LOG2E, nml2));
    float t0 = (p[0] + p[1]) + (p[2] + p[3]);
    float t1 = (p[4] + p[5]) + (p[6] + p[7]);
    float t2 = (p[8] + p[9]) + (p[10] + p[11]);
    float t3 = (p[12] + p[13]) + (p[14] + p[15]);
    l += xsum32((t0 + t1) + (t2 + t3));

    // pack to f16 pairs: w[i] = P at k-rows {crow(2i),crow(2i+1)}, crow offset +4hi.
    unsigned w[8];
#pragma unroll
    for (int i = 0; i < 8; ++i) w[i] = pk2(p[2 * i], p[2 * i + 1]);
    // pair exchange (w0<->w2),(w1<->w3),(w4<->w6),(w5<->w7): one shuffle each.
    // y = hb ? wLow : wHigh; partner's y is exactly what this lane needs.
    unsigned y0 = hb ? w[0] : w[2];  unsigned r0 = (unsigned)__shfl_xor((int)y0, 32);
    unsigned y1 = hb ? w[1] : w[3];  unsigned r1 = (unsigned)__shfl_xor((int)y1, 32);
    unsigned y2 = hb ? w[4] : w[6];  unsigned r2 = (unsigned)__shfl_xor((int)y2, 32);
    unsigned y3 = hb ? w[5] : w[7];  unsigned r3 = (unsigned)__shfl_xor((int)y3, 32);
    union { unsigned u[4]; half8 v; } f;
    f.u[0] = hb ? r0 : w[0];   // hi0: k{0,1}   hi1: k{8,9}
    f.u[1] = hb ? r1 : w[1];   // hi0: k{2,3}   hi1: k{10,11}
    f.u[2] = hb ? w[2] : r0;   // hi0: k{4,5}   hi1: k{12,13}
    f.u[3] = hb ? w[3] : r1;   // hi0: k{6,7}   hi1: k{14,15}
    pv0 = f.v;
    f.u[0] = hb ? r2 : w[4];
    f.u[1] = hb ? r3 : w[5];
    f.u[2] = hb ? w[6] : r2;
    f.u[3] = hb ? w[7] : r3;
    pv1 = f.v;
  };

  LOADT(0);
  for (int it = 0; it < NIT; ++it) {
    __syncthreads();
    STORET();
    if (it + 1 < NIT) LOADT(it + 1);
    __syncthreads();

    const _Float16* Kt = sm.s.K[wk];
    const _Float16* Vt = sm.s.Vt[wk];

    // ---- QK^T: each K fragment feeds both q-sets (2 MFMAs per LDS read)
    const int ksw = (lq & 7) << 3;
    f32x16 sA = {}, sB = {};
    __builtin_amdgcn_s_setprio(1);
#pragma unroll
    for (int c = 0; c < 4; ++c) {
      half8 a = *(const half8*)&Kt[(lq * DIM + c * 16 + hi * 8) ^ ksw];
      sA = __builtin_amdgcn_mfma_f32_32x32x16_f16(a, qfA[c], sA, 0, 0, 0);
      sB = __builtin_amdgcn_mfma_f32_32x32x16_f16(a, qfB[c], sB, 0, 0, 0);
    }
    __builtin_amdgcn_s_setprio(0);

    half8 pA0, pA1, pB0, pB1;
    softmax_set(sA, mA, lA, oA0, oA1, pA0, pA1);
    softmax_set(sB, mB, lB, oB0, oB1, pB0, pB1);

    // ---- PV: each V^T fragment feeds both q-sets
    const int d0 = lq, d1 = 32 + lq;
    const int sz0 = (d0 & 7) << 3, sz1 = (d1 & 7) << 3;
    __builtin_amdgcn_s_setprio(1);
    {
      half8 a = *(const half8*)&Vt[(d0 * KVB + 0 + hi * 8) ^ sz0];
      oA0 = __builtin_amdgcn_mfma_f32_32x32x16_f16(a, pA0, oA0, 0, 0, 0);
      oB0 = __builtin_amdgcn_mfma_f32_32x32x16_f16(a, pB0, oB0, 0, 0, 0);
    }
    {
      half8 a = *(const half8*)&Vt[(d1 * KVB + 0 + hi * 8) ^ sz1];
      oA1 = __builtin_amdgcn_mfma_f32_32x32x16_f16(a, pA0, oA1, 0, 0, 0);
      oB1 = __builtin_amdgcn_mfma_f32_32x32x16_f16(a, pB0, oB1, 0, 0, 0);
    }
    {
      half8 a = *(const half8*)&Vt[(d0 * KVB + 16 + hi * 8) ^ sz0];
      oA0 = __builtin_amdgcn_mfma_f32_32x32x16_f16(a, pA1, oA0, 0, 0, 0);
      oB0 = __builtin_amdgcn_mfma_f32_32x32x16_f16(a, pB1, oB0, 0, 0, 0);
    }
    {
      half8 a = *(const half8*)&Vt[(d1 * KVB + 16 + hi * 8) ^ sz1];
      oA1 = __builtin_amdgcn_mfma_f32_32x32x16_f16(a, pA1, oA1, 0, 0, 0);
      oB1 = __builtin_amdgcn_mfma_f32_32x32x16_f16(a, pB1, oB1, 0, 0, 0);
    }
    __builtin_amdgcn_s_setprio(0);
  }

  // ---- combine kv-parities via LDS (union reuse after staging done) ----
  __syncthreads();
  if (wk == 1) {
#pragma unroll
    for (int r = 0; r < 16; ++r) {
      sm.c.ob[wq][0][0][r * 64 + lane] = oA0[r];
      sm.c.ob[wq][0][1][r * 64 + lane] = oA1[r];
      sm.c.ob[wq][1][0][r * 64 + lane] = oB0[r];
      sm.c.ob[wq][1][1][r * 64 + lane] = oB1[r];
    }
    sm.c.ml[wq][0][0][lane] = mA; sm.c.ml[wq][0][1][lane] = lA;
    sm.c.ml[wq][1][0][lane] = mB; sm.c.ml[wq][1][1][lane] = lB;
  }
  __syncthreads();
  if (wk == 0) {
    auto emit = [&](int set, int qrow, const f32x16& o0, const f32x16& o1,
                    float m, float l) {
      const float mb = sm.c.ml[wq][set][0][lane];
      const float lb = sm.c.ml[wq][set][1][lane];
      const float mx = fmaxf(m, mb);
      const float ca = __builtin_amdgcn_exp2f((m - mx) * LOG2E);
      const float cb = __builtin_amdgcn_exp2f((mb - mx) * LOG2E);
      const float inv = 1.0f / (l * ca + lb * cb);
      float* op = O + base + (size_t)qrow * DIM;
#pragma unroll
      for (int g = 0; g < 4; ++g) {
        float4 r0, r1;
        r0.x = (o0[4*g+0] * ca + sm.c.ob[wq][set][0][(4*g+0)*64 + lane] * cb) * inv;
        r0.y = (o0[4*g+1] * ca + sm.c.ob[wq][set][0][(4*g+1)*64 + lane] * cb) * inv;
        r0.z = (o0[4*g+2] * ca + sm.c.ob[wq][set][0][(4*g+2)*64 + lane] * cb) * inv;
        r0.w = (o0[4*g+3] * ca + sm.c.ob[wq][set][0][(4*g+3)*64 + lane] * cb) * inv;
        r1.x = (o1[4*g+0] * ca + sm.c.ob[wq][set][1][(4*g+0)*64 + lane] * cb) * inv;
        r1.y = (o1[4*g+1] * ca + sm.c.ob[wq][set][1][(4*g+1)*64 + lane] * cb) * inv;
        r1.z = (o1[4*g+2] * ca + sm.c.ob[wq][set][1][(4*g+2)*64 + lane] * cb) * inv;
        r1.w = (o1[4*g+3] * ca + sm.c.ob[wq][set][1][(4*g+3)*64 + lane] * cb) * inv;
        *(float4*)(op + 8 * g + 4 * hi) = r0;        // d = 8g+4hi..+3
        *(float4*)(op + 32 + 8 * g + 4 * hi) = r1;   // d = 32+8g+4hi..+3
      }
    };
    emit(0, qr0,      oA0, oA1, mA, lA);
    emit(1, qr0 + 32, oB0, oB1, mB, lB);
  }
}

extern "C" void kernel_launch(void* const* d_in, const int* in_sizes, int n_in,
                              void* d_out, int out_size, void* d_ws, size_t ws_size,
                              hipStream_t stream) {
  const float* q = (const float*)d_in[0];
  const float* k = (const float*)d_in[1];
  const float* v = (const float*)d_in[2];
  float* o = (float*)d_out;
  attn_fwd<<<BH * (SEQ / QBLK), 256, 0, stream>>>(q, k, v, o);
}